// Round 4
// baseline (103.973 us; speedup 1.0000x reference)
//
#include <hip/hip_runtime.h>

// AAConv: 3x3 conv (256->256) + 1x1 conv (256->768 kqv) + 8-head attention
// (HW=1024, DKH=DVH=32), out = concat([conv_out, attn_out]) (8,512,32,32) fp32.
//
// R8: conv+attn FUSED into one dispatch (they are independent: conv reads
//   xT/WcT -> out[:,0:256]; attn reads kT/qT/vB -> out[:,256:512]).
//   Decode: xcd = bid&7 (batch = xcd, keeps R6/R7 L2 residency: 1.5MB attn
//   + 0.5MB xT + 1.15MB WcT = 3.2MB < 4MB), path = (bid>>3)&1 interleaves
//   32 attn + 32 conv resident blocks per XCD from t=0.
//   conv split to 1 output-row/block (grid half 512, halo 3 rows, wave tile
//   32co x 32n): fixes 1-block/CU occupancy starvation of R7 conv.
//   LDS unioned (32KB), __launch_bounds__(256,2).
// prep/kqv unchanged from R7. attn body unchanged from R7 (pointer-carved LDS).
//
// ws layout (bytes): vB @0 (4,194,304) | kT @4,194,304 (4,194,304)
//   | qT @8,388,608 (4,194,304) | xT @12,582,912 (4,194,304)
//   | WcT @16,777,216 (1,179,648) | WaT @17,956,864 (393,216)

typedef __attribute__((ext_vector_type(8))) short short8;
typedef __attribute__((ext_vector_type(4))) float f32x4;
typedef unsigned short u16;

// 1/sqrt(32) * log2(e): Q pre-scale folding softmax into exp2 domain.
#define QSCALE 0.25503487629898483f

__device__ inline u16 f2bf(float f) {
  unsigned u = __builtin_bit_cast(unsigned, f);
  return (u16)((u + 0x7FFFu + ((u >> 16) & 1u)) >> 16);
}
__device__ inline unsigned pack2bf(float a, float b) {
  return (unsigned)f2bf(a) | ((unsigned)f2bf(b) << 16);
}
// P-pack: round-half-up to bf16 then byte-perm the two hi16s together.
__device__ inline unsigned packP(float a, float b) {
  unsigned au = __builtin_bit_cast(unsigned, a) + 0x8000u;
  unsigned bu = __builtin_bit_cast(unsigned, b) + 0x8000u;
  return __builtin_amdgcn_perm(bu, au, 0x07060302u);
}
__device__ inline float hmax4(f32x4 v) {
  return fmaxf(fmaxf(v[0], v[1]), fmaxf(v[2], v[3]));
}
__device__ inline float hsum4(f32x4 v) { return (v[0] + v[1]) + (v[2] + v[3]); }

// ---------------------------------------------------------------------------
// prep: grid 320. (streaming, no reuse -> no swizzle)
// ---------------------------------------------------------------------------
__global__ __launch_bounds__(256) void prep_kernel(const float* __restrict__ x,
                                                   const float* __restrict__ cw,
                                                   const float* __restrict__ aw,
                                                   u16* __restrict__ xT,
                                                   u16* __restrict__ WcT,
                                                   u16* __restrict__ WaT) {
  __shared__ float T[64][65];
  int bid = blockIdx.x, tid = threadIdx.x;

  if (bid < 128) {
    int b = bid >> 4, n0 = (bid & 15) * 64;
#pragma unroll
    for (int rep = 0; rep < 2; ++rep) {
      int flat = rep * 256 + tid;          // 0..511
      int n = flat & 63, cg = flat >> 6;   // cg 0..7 -> 32 ci each
#pragma unroll
      for (int q = 0; q < 4; ++q) {
        short8 pk;
#pragma unroll
        for (int j = 0; j < 8; ++j)
          pk[j] =
              (short)f2bf(x[(b * 256 + cg * 32 + q * 8 + j) * 1024 + n0 + n]);
        *(short8*)&xT[(b * 1024 + n0 + n) * 256 + cg * 32 + q * 8] = pk;
      }
    }
    return;
  }

  int tt = bid - 128;
  int chunk = tt >> 4, t = tt & 15;
  int ci0 = (t & 3) * 64, r0 = (t >> 2) * 64;
  bool isconv = chunk < 9;
  float scale = (chunk == 10) ? QSCALE : 1.0f;

#pragma unroll
  for (int rep = 0; rep < 16; ++rep) {
    int flat = rep * 256 + tid;
    int i = flat >> 6, j = flat & 63;     // i = ci-local, j = dst-row-local
    T[i][j] = isconv ? cw[(chunk * 256 + ci0 + i) * 256 + r0 + j]
                     : aw[(ci0 + i) * 768 + (chunk - 9) * 256 + r0 + j];
  }
  __syncthreads();
#pragma unroll
  for (int rep = 0; rep < 4; ++rep) {
    int flat = rep * 256 + tid;
    int jj = flat >> 4, qq = flat & 15;   // dst row r0+jj, ci ci0+qq*4
    float v0 = T[qq * 4 + 0][jj] * scale;
    float v1 = T[qq * 4 + 1][jj] * scale;
    float v2 = T[qq * 4 + 2][jj] * scale;
    float v3 = T[qq * 4 + 3][jj] * scale;
    uint2 pk = {pack2bf(v0, v1), pack2bf(v2, v3)};
    if (isconv)
      *(uint2*)&WcT[(chunk * 256 + r0 + jj) * 256 + ci0 + qq * 4] = pk;
    else
      *(uint2*)&WaT[((chunk - 9) * 256 + r0 + jj) * 256 + ci0 + qq * 4] = pk;
  }
}

// ---------------------------------------------------------------------------
// kqv: GEMM [768x256]x[256x1024] per batch. grid 768. b = bid&7 (XCD-local).
// ---------------------------------------------------------------------------
__global__ __launch_bounds__(256) void kqv_kernel(const u16* __restrict__ xT,
                                                  const u16* __restrict__ WaT,
                                                  const float* __restrict__ ab,
                                                  u16* __restrict__ kT,
                                                  u16* __restrict__ qT,
                                                  u16* __restrict__ vB) {
  __shared__ __align__(16) u16 Tt[64 * 136];  // [n-local 64][o-local 128 +8 pad]
  int bid = blockIdx.x;
  int b = bid & 7, idx = bid >> 3;       // XCD-local batch
  int ot = idx >> 4, nt = idx & 15;      // idx 0..95 -> ot 0..5, nt 0..15
  int tid = threadIdx.x, wave = tid >> 6, lane = tid & 63;
  int ln = lane & 15, g = lane >> 4;
  int o0 = ot * 128 + (wave & 1) * 64;
  int n0 = nt * 64 + (wave >> 1) * 32;
  const u16* xb = xT + b * 1024 * 256;
  f32x4 acc[4][2];
#pragma unroll
  for (int i = 0; i < 4; ++i)
#pragma unroll
    for (int j = 0; j < 2; ++j) acc[i][j] = (f32x4){0.f, 0.f, 0.f, 0.f};

#pragma unroll
  for (int c0 = 0; c0 < 256; c0 += 32) {
    int ko = c0 + g * 8;
    short8 a0 = *(const short8*)&WaT[(o0 + ln) * 256 + ko];
    short8 a1 = *(const short8*)&WaT[(o0 + 16 + ln) * 256 + ko];
    short8 a2 = *(const short8*)&WaT[(o0 + 32 + ln) * 256 + ko];
    short8 a3 = *(const short8*)&WaT[(o0 + 48 + ln) * 256 + ko];
    short8 b0 = *(const short8*)&xb[(n0 + ln) * 256 + ko];
    short8 b1 = *(const short8*)&xb[(n0 + 16 + ln) * 256 + ko];
    acc[0][0] = __builtin_amdgcn_mfma_f32_16x16x32_bf16(a0, b0, acc[0][0], 0, 0, 0);
    acc[0][1] = __builtin_amdgcn_mfma_f32_16x16x32_bf16(a0, b1, acc[0][1], 0, 0, 0);
    acc[1][0] = __builtin_amdgcn_mfma_f32_16x16x32_bf16(a1, b0, acc[1][0], 0, 0, 0);
    acc[1][1] = __builtin_amdgcn_mfma_f32_16x16x32_bf16(a1, b1, acc[1][1], 0, 0, 0);
    acc[2][0] = __builtin_amdgcn_mfma_f32_16x16x32_bf16(a2, b0, acc[2][0], 0, 0, 0);
    acc[2][1] = __builtin_amdgcn_mfma_f32_16x16x32_bf16(a2, b1, acc[2][1], 0, 0, 0);
    acc[3][0] = __builtin_amdgcn_mfma_f32_16x16x32_bf16(a3, b0, acc[3][0], 0, 0, 0);
    acc[3][1] = __builtin_amdgcn_mfma_f32_16x16x32_bf16(a3, b1, acc[3][1], 0, 0, 0);
  }

  if (ot >= 4) {
    // V: natural [dv][m] layout, scalar bf16 stores.
#pragma unroll
    for (int it = 0; it < 4; ++it)
#pragma unroll
      for (int r = 0; r < 4; ++r) {
        int o = o0 + it * 16 + g * 4 + r;
        float bias = ab[o];
#pragma unroll
        for (int jt = 0; jt < 2; ++jt) {
          int n = n0 + jt * 16 + ln;
          vB[(b * 256 + (o - 512)) * 1024 + n] = f2bf(acc[it][jt][r] + bias);
        }
      }
    return;
  }

  // K/Q: transpose 128o x 64n tile via LDS, write [b][h][n][d] vectorized.
  bool isQ = (ot >= 2);
  float bs = isQ ? QSCALE : 1.0f;
  int olb = (wave & 1) * 64;
  int nlb = (wave >> 1) * 32;
#pragma unroll
  for (int it = 0; it < 4; ++it)
#pragma unroll
    for (int jt = 0; jt < 2; ++jt) {
      int ol = olb + it * 16 + g * 4;
      int nl = nlb + jt * 16 + ln;
      int og = ot * 128 + ol;
      float v0 = acc[it][jt][0] + ab[og + 0] * bs;
      float v1 = acc[it][jt][1] + ab[og + 1] * bs;
      float v2 = acc[it][jt][2] + ab[og + 2] * bs;
      float v3 = acc[it][jt][3] + ab[og + 3] * bs;
      uint2 pk = {pack2bf(v0, v1), pack2bf(v2, v3)};
      *(uint2*)&Tt[nl * 136 + ol] = pk;
    }
  __syncthreads();
  u16* dst = isQ ? qT : kT;
#pragma unroll
  for (int rep = 0; rep < 4; ++rep) {
    int flat = rep * 256 + tid;
    int o8 = flat & 15, nl = flat >> 4;
    short8 v = *(const short8*)&Tt[nl * 136 + o8 * 8];
    int og256 = (ot & 1) * 128 + o8 * 8;   // o within the 256-row K (or Q) range
    int hh = og256 >> 5, d0 = og256 & 31;
    int ng = nt * 64 + nl;
    *(short8*)&dst[((b * 8 + hh) * 1024 + ng) * 32 + d0] = v;
  }
}

// ---------------------------------------------------------------------------
// FUSED conv + attn. grid 1024. xcd = bid&7 -> batch b; sub = bid>>3;
// path = sub&1 (0 = attn, 1 = conv); idx = sub>>1 (0..63).
//   attn: h = idx>>3, qt = idx&7 (128 q-rows per block, 4 waves x 32).
//   conv: hp = idx>>1 (one output h-row), coh = idx&1 (128-co half).
// LDS union: attn kv(16KB)+p_s(16KB) = 32KB; conv Xc 3*34*72 u16 = 14.7KB.
// ---------------------------------------------------------------------------
__global__ __launch_bounds__(256, 2) void conv_attn_kernel(
    const u16* __restrict__ xT, const u16* __restrict__ WcT,
    const float* __restrict__ cb, const u16* __restrict__ kT,
    const u16* __restrict__ qT, const u16* __restrict__ vB,
    float* __restrict__ out) {
  __shared__ __align__(16) unsigned char smem[32768];

  int bid = blockIdx.x;
  int b = bid & 7;                  // XCD-local batch
  int sub = bid >> 3;               // 0..127
  int path = sub & 1;
  int idx = sub >> 1;               // 0..63
  int tid = threadIdx.x;
  int wave = tid >> 6, lane = tid & 63;
  int ln = lane & 15, g = lane >> 4;

  if (path == 1) {
    // ======================= conv: one output h-row =======================
    u16* Xc = (u16*)smem;           // [3*34 rows][72], 14.7 KB
    int hp = idx >> 1, coh = idx & 1;
    int h0 = hp;
    int co0 = coh * 128 + wave * 32;

    f32x4 acc[2][2];
#pragma unroll
    for (int i = 0; i < 2; ++i)
#pragma unroll
      for (int j = 0; j < 2; ++j) acc[i][j] = (f32x4){0.f, 0.f, 0.f, 0.f};

    if (tid < 192) {  // zero halo columns w'=0,33 for 3 rows
      int rp = tid >> 6, rest = tid & 63;
      int which = rest >> 5, cp = rest & 31;
      *(unsigned*)&Xc[(rp * 34 + which * 33) * 72 + cp * 2] = 0u;
    }

    for (int c0 = 0; c0 < 256; c0 += 64) {
      __syncthreads();
#pragma unroll
      for (int rep = 0; rep < 3; ++rep) {
        int flat = rep * 256 + tid;
        int cg = flat & 7, w = (flat >> 3) & 31, rp = flat >> 8;  // rp 0..2
        int row = h0 - 1 + rp;
        short8 v = {0, 0, 0, 0, 0, 0, 0, 0};
        if ((unsigned)row < 32u)
          v = *(const short8*)&xT[(b * 1024 + row * 32 + w) * 256 + c0 + cg * 8];
        *(short8*)&Xc[(rp * 34 + w + 1) * 72 + cg * 8] = v;
      }
      __syncthreads();
#pragma unroll
      for (int ks = 0; ks < 2; ++ks) {
        int ko = c0 + ks * 32 + g * 8;
        int klo = ks * 32 + g * 8;
#pragma unroll
        for (int r = 0; r < 3; ++r)
#pragma unroll
          for (int s = 0; s < 3; ++s) {
            int tap = r * 3 + s;
            short8 a0 = *(const short8*)&WcT[(tap * 256 + co0 + ln) * 256 + ko];
            short8 a1 =
                *(const short8*)&WcT[(tap * 256 + co0 + 16 + ln) * 256 + ko];
#pragma unroll
            for (int jt = 0; jt < 2; ++jt) {
              int rowp = r * 34 + jt * 16 + ln + s;
              short8 bf = *(const short8*)&Xc[rowp * 72 + klo];
              acc[0][jt] = __builtin_amdgcn_mfma_f32_16x16x32_bf16(
                  a0, bf, acc[0][jt], 0, 0, 0);
              acc[1][jt] = __builtin_amdgcn_mfma_f32_16x16x32_bf16(
                  a1, bf, acc[1][jt], 0, 0, 0);
            }
          }
      }
    }

#pragma unroll
    for (int it = 0; it < 2; ++it)
#pragma unroll
      for (int r4 = 0; r4 < 4; ++r4) {
        int co = co0 + it * 16 + g * 4 + r4;
        float bias = cb[co];
#pragma unroll
        for (int jt = 0; jt < 2; ++jt) {
          int w = jt * 16 + ln;
          out[((b * 512 + co) * 32 + h0) * 32 + w] = acc[it][jt][r4] + bias;
        }
      }
    return;
  }

  // ========================== attn (R7 body) ==========================
  u16* kvb = (u16*)smem;                  // kv[2][4096]: buf*4096
  u16* ps = (u16*)(smem + 16384);         // p_s[4][2][1024]
  int h = idx >> 3, qt = idx & 7;
  int nw = qt * 128 + wave * 32;

  const u16* kb = kT + (b * 8 + h) * (1024 * 32);
  const u16* qb = qT + (b * 8 + h) * (1024 * 32);
  const u16* vb = vB + (b * 256 + h * 32) * 1024;

  short8 qf0 = *(const short8*)&qb[(nw + ln) * 32 + g * 8];
  short8 qf1 = *(const short8*)&qb[(nw + 16 + ln) * 32 + g * 8];

  // staging coords: K piece (row sr, 16B slot ss), V piece (row dvr, slot vs)
  int sr = tid >> 2, ss = tid & 3;
  int dvr = tid >> 3, vs = tid & 7;
  const u16* ksrc = kb + sr * 32 + ss * 8;
  const u16* vsrc = vb + dvr * 1024 + vs * 8;
  int kdsw = sr * 32 + ((ss ^ ((sr + (sr >> 2)) & 3)) * 8);
  int vdsw = 2048 + dvr * 64 + ((vs ^ (dvr & 7)) * 8);

  // per-lane fragment swizzle constants
  int skl = (ln + (ln >> 2)) & 3;
  int svl = ln & 7;
  int kfo = ln * 32 + ((g ^ skl) * 8);   // K frag u16 offset (+ kt*512)

  f32x4 o00 = {0.f, 0.f, 0.f, 0.f}, o01 = o00, o10 = o00, o11 = o00;
  float mx0 = -1e30f, mx1 = -1e30f, l0 = 0.f, l1 = 0.f;
  u16* pw0 = ps + wave * 2048;
  u16* pw1 = pw0 + 1024;

  // prologue: tile 0 -> buf0; issue tile 1 loads
  short8 kp = *(const short8*)ksrc;
  short8 vp = *(const short8*)vsrc;
  *(short8*)&kvb[kdsw] = kp;
  *(short8*)&kvb[vdsw] = vp;
  __syncthreads();
  kp = *(const short8*)(ksrc + 2048);
  vp = *(const short8*)(vsrc + 64);

  for (int mt = 0; mt < 16; ++mt) {
    u16* bc = kvb + (mt & 1) * 4096;
    if (mt < 15) {
      u16* bn = kvb + ((mt + 1) & 1) * 4096;
      *(short8*)&bn[kdsw] = kp;
      *(short8*)&bn[vdsw] = vp;
    }
    if (mt < 14) {
      kp = *(const short8*)(ksrc + (mt + 2) * 2048);
      vp = *(const short8*)(vsrc + (mt + 2) * 64);
    }

    // ---- QK^T ----
    short8 ka0 = *(const short8*)&bc[0 * 512 + kfo];
    short8 ka1 = *(const short8*)&bc[1 * 512 + kfo];
    short8 ka2 = *(const short8*)&bc[2 * 512 + kfo];
    short8 ka3 = *(const short8*)&bc[3 * 512 + kfo];
    f32x4 z = {0.f, 0.f, 0.f, 0.f};
    f32x4 s0[4], s1[4];
    __builtin_amdgcn_s_setprio(1);
    s0[0] = __builtin_amdgcn_mfma_f32_16x16x32_bf16(ka0, qf0, z, 0, 0, 0);
    s1[0] = __builtin_amdgcn_mfma_f32_16x16x32_bf16(ka0, qf1, z, 0, 0, 0);
    s0[1] = __builtin_amdgcn_mfma_f32_16x16x32_bf16(ka1, qf0, z, 0, 0, 0);
    s1[1] = __builtin_amdgcn_mfma_f32_16x16x32_bf16(ka1, qf1, z, 0, 0, 0);
    s0[2] = __builtin_amdgcn_mfma_f32_16x16x32_bf16(ka2, qf0, z, 0, 0, 0);
    s1[2] = __builtin_amdgcn_mfma_f32_16x16x32_bf16(ka2, qf1, z, 0, 0, 0);
    s0[3] = __builtin_amdgcn_mfma_f32_16x16x32_bf16(ka3, qf0, z, 0, 0, 0);
    s1[3] = __builtin_amdgcn_mfma_f32_16x16x32_bf16(ka3, qf1, z, 0, 0, 0);
    __builtin_amdgcn_s_setprio(0);

    // V fragments (LDS, current buffer) -- prefetch for PV
    short8 va00 = *(const short8*)&bc[2048 + ln * 64 + ((g ^ svl) * 8)];
    short8 va01 = *(const short8*)&bc[2048 + (16 + ln) * 64 + ((g ^ svl) * 8)];
    short8 va10 = *(const short8*)&bc[2048 + ln * 64 + (((4 + g) ^ svl) * 8)];
    short8 va11 =
        *(const short8*)&bc[2048 + (16 + ln) * 64 + (((4 + g) ^ svl) * 8)];

    // ---- online softmax (exp2 domain), tree reductions ----
    float tmax0 = fmaxf(fmaxf(hmax4(s0[0]), hmax4(s0[1])),
                        fmaxf(hmax4(s0[2]), hmax4(s0[3])));
    float tmax1 = fmaxf(fmaxf(hmax4(s1[0]), hmax4(s1[1])),
                        fmaxf(hmax4(s1[2]), hmax4(s1[3])));
    tmax0 = fmaxf(tmax0, __shfl_xor(tmax0, 16));
    tmax0 = fmaxf(tmax0, __shfl_xor(tmax0, 32));
    tmax1 = fmaxf(tmax1, __shfl_xor(tmax1, 16));
    tmax1 = fmaxf(tmax1, __shfl_xor(tmax1, 32));

    if (!__all(fmaxf(tmax0 - mx0, tmax1 - mx1) <= 8.0f)) {
      float nm0 = fmaxf(mx0, tmax0), nm1 = fmaxf(mx1, tmax1);
      float sc0 = __builtin_amdgcn_exp2f(mx0 - nm0);
      float sc1 = __builtin_amdgcn_exp2f(mx1 - nm1);
#pragma unroll
      for (int r = 0; r < 4; ++r) {
        o00[r] *= sc0; o01[r] *= sc0;
        o10[r] *= sc1; o11[r] *= sc1;
      }
      l0 *= sc0; l1 *= sc1;
      mx0 = nm0; mx1 = nm1;
    }

#pragma unroll
    for (int kt = 0; kt < 4; ++kt)
#pragma unroll
      for (int r = 0; r < 4; ++r) {
        s0[kt][r] = __builtin_amdgcn_exp2f(s0[kt][r] - mx0);
        s1[kt][r] = __builtin_amdgcn_exp2f(s1[kt][r] - mx1);
      }
    float ts0 = (hsum4(s0[0]) + hsum4(s0[1])) + (hsum4(s0[2]) + hsum4(s0[3]));
    float ts1 = (hsum4(s1[0]) + hsum4(s1[1])) + (hsum4(s1[2]) + hsum4(s1[3]));
    ts0 += __shfl_xor(ts0, 16); ts0 += __shfl_xor(ts0, 32);
    ts1 += __shfl_xor(ts1, 16); ts1 += __shfl_xor(ts1, 32);
    l0 += ts0; l1 += ts1;

    // ---- P -> bf16, swizzled LDS, b64 writes ----
#pragma unroll
    for (int kt = 0; kt < 4; ++kt) {
      int po = ln * 64 + (((kt * 2 + (g >> 1)) ^ svl) * 8) + (g & 1) * 4;
      uint2 w0 = {packP(s0[kt][0], s0[kt][1]), packP(s0[kt][2], s0[kt][3])};
      *(uint2*)&pw0[po] = w0;
      uint2 w1 = {packP(s1[kt][0], s1[kt][1]), packP(s1[kt][2], s1[kt][3])};
      *(uint2*)&pw1[po] = w1;
    }
    short8 pb00 = *(const short8*)&pw0[ln * 64 + ((g ^ svl) * 8)];
    short8 pb01 = *(const short8*)&pw0[ln * 64 + (((4 + g) ^ svl) * 8)];
    short8 pb10 = *(const short8*)&pw1[ln * 64 + ((g ^ svl) * 8)];
    short8 pb11 = *(const short8*)&pw1[ln * 64 + (((4 + g) ^ svl) * 8)];

    // ---- PV ----
    __builtin_amdgcn_s_setprio(1);
    o00 = __builtin_amdgcn_mfma_f32_16x16x32_bf16(va00, pb00, o00, 0, 0, 0);
    o01 = __builtin_amdgcn_mfma_f32_16x16x32_bf16(va01, pb00, o01, 0, 0, 0);
    o00 = __builtin_amdgcn_mfma_f32_16x16x32_bf16(va10, pb01, o00, 0, 0, 0);
    o01 = __builtin_amdgcn_mfma_f32_16x16x32_bf16(va11, pb01, o01, 0, 0, 0);
    o10 = __builtin_amdgcn_mfma_f32_16x16x32_bf16(va00, pb10, o10, 0, 0, 0);
    o11 = __builtin_amdgcn_mfma_f32_16x16x32_bf16(va01, pb10, o11, 0, 0, 0);
    o10 = __builtin_amdgcn_mfma_f32_16x16x32_bf16(va10, pb11, o10, 0, 0, 0);
    o11 = __builtin_amdgcn_mfma_f32_16x16x32_bf16(va11, pb11, o11, 0, 0, 0);
    __builtin_amdgcn_s_setprio(0);

    __syncthreads();
  }

  float rl0 = 1.f / l0, rl1 = 1.f / l1;
  float* obase = out + (b * 512 + 256 + h * 32) * 1024;
  float* ob0 = obase + nw + ln;
  float* ob1 = obase + nw + 16 + ln;
#pragma unroll
  for (int r = 0; r < 4; ++r) {
    int dv0 = g * 4 + r;
    ob0[dv0 * 1024] = o00[r] * rl0;
    ob0[(16 + dv0) * 1024] = o01[r] * rl0;
    ob1[dv0 * 1024] = o10[r] * rl1;
    ob1[(16 + dv0) * 1024] = o11[r] * rl1;
  }
}

// ---------------------------------------------------------------------------
extern "C" void kernel_launch(void* const* d_in, const int* in_sizes, int n_in,
                              void* d_out, int out_size, void* d_ws,
                              size_t ws_size, hipStream_t stream) {
  const float* x  = (const float*)d_in[0];
  const float* cw = (const float*)d_in[1];
  const float* cb = (const float*)d_in[2];
  const float* aw = (const float*)d_in[3];
  const float* ab = (const float*)d_in[4];
  float* out = (float*)d_out;

  char* ws = (char*)d_ws;
  u16* vB  = (u16*)ws;                           //  4,194,304 B
  u16* kT  = (u16*)(ws + 4194304);               //  4,194,304 B
  u16* qT  = (u16*)(ws + 8388608);               //  4,194,304 B
  u16* xT  = (u16*)(ws + 12582912);              //  4,194,304 B
  u16* WcT = (u16*)(ws + 16777216);              //  1,179,648 B
  u16* WaT = (u16*)(ws + 17956864);              //    393,216 B

  prep_kernel<<<320, 256, 0, stream>>>(x, cw, aw, xT, WcT, WaT);
  kqv_kernel<<<768, 256, 0, stream>>>(xT, WaT, ab, kT, qT, vB);
  conv_attn_kernel<<<1024, 256, 0, stream>>>(xT, WcT, cb, kT, qT, vB, out);
}

// Round 5
// 68.282 us; speedup vs baseline: 1.5227x; 1.5227x over previous
//
#include <hip/hip_runtime.h>

// AAConv: 3x3 conv (256->256) + 1x1 conv (256->768 kqv) + 8-head attention
// (HW=1024, DKH=DVH=32), out = concat([conv_out, attn_out]) (8,512,32,32) fp32.
//
// R9: fusion kept, conv body reverted to R7 geometry. R8's regression was the
//   1-row conv split (2x WcT L2 traffic/XCD, 1.5x halo, worse MFMA:ds ratio),
//   not the fusion. Grid 768: xcd = bid&7 -> batch; sub = bid>>3 (0..95);
//   rem = sub%3: rem==2 -> conv (idx 0..31: 2 h-rows, R7 tile), else attn
//   (idx 0..63). Per XCD: 32 conv + 64 attn interleaved 1:2.
// prep/kqv unchanged from R7. attn body unchanged from R7.
//
// ws layout (bytes): vB @0 (4,194,304) | kT @4,194,304 (4,194,304)
//   | qT @8,388,608 (4,194,304) | xT @12,582,912 (4,194,304)
//   | WcT @16,777,216 (1,179,648) | WaT @17,956,864 (393,216)

typedef __attribute__((ext_vector_type(8))) short short8;
typedef __attribute__((ext_vector_type(4))) float f32x4;
typedef unsigned short u16;

// 1/sqrt(32) * log2(e): Q pre-scale folding softmax into exp2 domain.
#define QSCALE 0.25503487629898483f

__device__ inline u16 f2bf(float f) {
  unsigned u = __builtin_bit_cast(unsigned, f);
  return (u16)((u + 0x7FFFu + ((u >> 16) & 1u)) >> 16);
}
__device__ inline unsigned pack2bf(float a, float b) {
  return (unsigned)f2bf(a) | ((unsigned)f2bf(b) << 16);
}
// P-pack: round-half-up to bf16 then byte-perm the two hi16s together.
__device__ inline unsigned packP(float a, float b) {
  unsigned au = __builtin_bit_cast(unsigned, a) + 0x8000u;
  unsigned bu = __builtin_bit_cast(unsigned, b) + 0x8000u;
  return __builtin_amdgcn_perm(bu, au, 0x07060302u);
}
__device__ inline float hmax4(f32x4 v) {
  return fmaxf(fmaxf(v[0], v[1]), fmaxf(v[2], v[3]));
}
__device__ inline float hsum4(f32x4 v) { return (v[0] + v[1]) + (v[2] + v[3]); }

// ---------------------------------------------------------------------------
// prep: grid 320. (streaming, no reuse -> no swizzle)
// ---------------------------------------------------------------------------
__global__ __launch_bounds__(256) void prep_kernel(const float* __restrict__ x,
                                                   const float* __restrict__ cw,
                                                   const float* __restrict__ aw,
                                                   u16* __restrict__ xT,
                                                   u16* __restrict__ WcT,
                                                   u16* __restrict__ WaT) {
  __shared__ float T[64][65];
  int bid = blockIdx.x, tid = threadIdx.x;

  if (bid < 128) {
    int b = bid >> 4, n0 = (bid & 15) * 64;
#pragma unroll
    for (int rep = 0; rep < 2; ++rep) {
      int flat = rep * 256 + tid;          // 0..511
      int n = flat & 63, cg = flat >> 6;   // cg 0..7 -> 32 ci each
#pragma unroll
      for (int q = 0; q < 4; ++q) {
        short8 pk;
#pragma unroll
        for (int j = 0; j < 8; ++j)
          pk[j] =
              (short)f2bf(x[(b * 256 + cg * 32 + q * 8 + j) * 1024 + n0 + n]);
        *(short8*)&xT[(b * 1024 + n0 + n) * 256 + cg * 32 + q * 8] = pk;
      }
    }
    return;
  }

  int tt = bid - 128;
  int chunk = tt >> 4, t = tt & 15;
  int ci0 = (t & 3) * 64, r0 = (t >> 2) * 64;
  bool isconv = chunk < 9;
  float scale = (chunk == 10) ? QSCALE : 1.0f;

#pragma unroll
  for (int rep = 0; rep < 16; ++rep) {
    int flat = rep * 256 + tid;
    int i = flat >> 6, j = flat & 63;     // i = ci-local, j = dst-row-local
    T[i][j] = isconv ? cw[(chunk * 256 + ci0 + i) * 256 + r0 + j]
                     : aw[(ci0 + i) * 768 + (chunk - 9) * 256 + r0 + j];
  }
  __syncthreads();
#pragma unroll
  for (int rep = 0; rep < 4; ++rep) {
    int flat = rep * 256 + tid;
    int jj = flat >> 4, qq = flat & 15;   // dst row r0+jj, ci ci0+qq*4
    float v0 = T[qq * 4 + 0][jj] * scale;
    float v1 = T[qq * 4 + 1][jj] * scale;
    float v2 = T[qq * 4 + 2][jj] * scale;
    float v3 = T[qq * 4 + 3][jj] * scale;
    uint2 pk = {pack2bf(v0, v1), pack2bf(v2, v3)};
    if (isconv)
      *(uint2*)&WcT[(chunk * 256 + r0 + jj) * 256 + ci0 + qq * 4] = pk;
    else
      *(uint2*)&WaT[((chunk - 9) * 256 + r0 + jj) * 256 + ci0 + qq * 4] = pk;
  }
}

// ---------------------------------------------------------------------------
// kqv: GEMM [768x256]x[256x1024] per batch. grid 768. b = bid&7 (XCD-local).
// ---------------------------------------------------------------------------
__global__ __launch_bounds__(256) void kqv_kernel(const u16* __restrict__ xT,
                                                  const u16* __restrict__ WaT,
                                                  const float* __restrict__ ab,
                                                  u16* __restrict__ kT,
                                                  u16* __restrict__ qT,
                                                  u16* __restrict__ vB) {
  __shared__ __align__(16) u16 Tt[64 * 136];  // [n-local 64][o-local 128 +8 pad]
  int bid = blockIdx.x;
  int b = bid & 7, idx = bid >> 3;       // XCD-local batch
  int ot = idx >> 4, nt = idx & 15;      // idx 0..95 -> ot 0..5, nt 0..15
  int tid = threadIdx.x, wave = tid >> 6, lane = tid & 63;
  int ln = lane & 15, g = lane >> 4;
  int o0 = ot * 128 + (wave & 1) * 64;
  int n0 = nt * 64 + (wave >> 1) * 32;
  const u16* xb = xT + b * 1024 * 256;
  f32x4 acc[4][2];
#pragma unroll
  for (int i = 0; i < 4; ++i)
#pragma unroll
    for (int j = 0; j < 2; ++j) acc[i][j] = (f32x4){0.f, 0.f, 0.f, 0.f};

#pragma unroll
  for (int c0 = 0; c0 < 256; c0 += 32) {
    int ko = c0 + g * 8;
    short8 a0 = *(const short8*)&WaT[(o0 + ln) * 256 + ko];
    short8 a1 = *(const short8*)&WaT[(o0 + 16 + ln) * 256 + ko];
    short8 a2 = *(const short8*)&WaT[(o0 + 32 + ln) * 256 + ko];
    short8 a3 = *(const short8*)&WaT[(o0 + 48 + ln) * 256 + ko];
    short8 b0 = *(const short8*)&xb[(n0 + ln) * 256 + ko];
    short8 b1 = *(const short8*)&xb[(n0 + 16 + ln) * 256 + ko];
    acc[0][0] = __builtin_amdgcn_mfma_f32_16x16x32_bf16(a0, b0, acc[0][0], 0, 0, 0);
    acc[0][1] = __builtin_amdgcn_mfma_f32_16x16x32_bf16(a0, b1, acc[0][1], 0, 0, 0);
    acc[1][0] = __builtin_amdgcn_mfma_f32_16x16x32_bf16(a1, b0, acc[1][0], 0, 0, 0);
    acc[1][1] = __builtin_amdgcn_mfma_f32_16x16x32_bf16(a1, b1, acc[1][1], 0, 0, 0);
    acc[2][0] = __builtin_amdgcn_mfma_f32_16x16x32_bf16(a2, b0, acc[2][0], 0, 0, 0);
    acc[2][1] = __builtin_amdgcn_mfma_f32_16x16x32_bf16(a2, b1, acc[2][1], 0, 0, 0);
    acc[3][0] = __builtin_amdgcn_mfma_f32_16x16x32_bf16(a3, b0, acc[3][0], 0, 0, 0);
    acc[3][1] = __builtin_amdgcn_mfma_f32_16x16x32_bf16(a3, b1, acc[3][1], 0, 0, 0);
  }

  if (ot >= 4) {
    // V: natural [dv][m] layout, scalar bf16 stores.
#pragma unroll
    for (int it = 0; it < 4; ++it)
#pragma unroll
      for (int r = 0; r < 4; ++r) {
        int o = o0 + it * 16 + g * 4 + r;
        float bias = ab[o];
#pragma unroll
        for (int jt = 0; jt < 2; ++jt) {
          int n = n0 + jt * 16 + ln;
          vB[(b * 256 + (o - 512)) * 1024 + n] = f2bf(acc[it][jt][r] + bias);
        }
      }
    return;
  }

  // K/Q: transpose 128o x 64n tile via LDS, write [b][h][n][d] vectorized.
  bool isQ = (ot >= 2);
  float bs = isQ ? QSCALE : 1.0f;
  int olb = (wave & 1) * 64;
  int nlb = (wave >> 1) * 32;
#pragma unroll
  for (int it = 0; it < 4; ++it)
#pragma unroll
    for (int jt = 0; jt < 2; ++jt) {
      int ol = olb + it * 16 + g * 4;
      int nl = nlb + jt * 16 + ln;
      int og = ot * 128 + ol;
      float v0 = acc[it][jt][0] + ab[og + 0] * bs;
      float v1 = acc[it][jt][1] + ab[og + 1] * bs;
      float v2 = acc[it][jt][2] + ab[og + 2] * bs;
      float v3 = acc[it][jt][3] + ab[og + 3] * bs;
      uint2 pk = {pack2bf(v0, v1), pack2bf(v2, v3)};
      *(uint2*)&Tt[nl * 136 + ol] = pk;
    }
  __syncthreads();
  u16* dst = isQ ? qT : kT;
#pragma unroll
  for (int rep = 0; rep < 4; ++rep) {
    int flat = rep * 256 + tid;
    int o8 = flat & 15, nl = flat >> 4;
    short8 v = *(const short8*)&Tt[nl * 136 + o8 * 8];
    int og256 = (ot & 1) * 128 + o8 * 8;   // o within the 256-row K (or Q) range
    int hh = og256 >> 5, d0 = og256 & 31;
    int ng = nt * 64 + nl;
    *(short8*)&dst[((b * 8 + hh) * 1024 + ng) * 32 + d0] = v;
  }
}

// ---------------------------------------------------------------------------
// FUSED conv + attn. grid 768. xcd = bid&7 -> batch b; sub = bid>>3 (0..95);
// rem = sub%3: rem==2 -> conv idx=sub/3 (0..31), else attn idx=(sub/3)*2+rem.
//   conv (R7 geometry): hp = idx>>1 (2 output h-rows), coh = idx&1.
//   attn: h = idx>>3, qt = idx&7 (128 q-rows per block, 4 waves x 32).
// LDS union: attn kv(16KB)+p_s(16KB) = 32KB; conv Xc 4*34*72 u16 = 19.6KB.
// ---------------------------------------------------------------------------
__global__ __launch_bounds__(256, 2) void conv_attn_kernel(
    const u16* __restrict__ xT, const u16* __restrict__ WcT,
    const float* __restrict__ cb, const u16* __restrict__ kT,
    const u16* __restrict__ qT, const u16* __restrict__ vB,
    float* __restrict__ out) {
  __shared__ __align__(16) unsigned char smem[32768];

  int bid = blockIdx.x;
  int b = bid & 7;                  // XCD-local batch
  int sub = bid >> 3;               // 0..95
  int trip = sub / 3;
  int rem = sub - trip * 3;
  int tid = threadIdx.x;
  int wave = tid >> 6, lane = tid & 63;
  int ln = lane & 15, g = lane >> 4;

  if (rem == 2) {
    // =================== conv: R7 body (2 output h-rows) ===================
    u16* Xc = (u16*)smem;           // [4*34 rows][72], 19.6 KB
    int hp = trip >> 1, coh = trip & 1;
    int h0 = hp * 2;
    int co0 = coh * 128 + wave * 32;

    f32x4 acc[2][4];
#pragma unroll
    for (int i = 0; i < 2; ++i)
#pragma unroll
      for (int j = 0; j < 4; ++j) acc[i][j] = (f32x4){0.f, 0.f, 0.f, 0.f};

    {
      int rp = tid >> 6, rest = tid & 63;
      int which = rest >> 5, cp = rest & 31;
      *(unsigned*)&Xc[(rp * 34 + which * 33) * 72 + cp * 2] = 0u;
    }

    for (int c0 = 0; c0 < 256; c0 += 64) {
      __syncthreads();
#pragma unroll
      for (int rep = 0; rep < 4; ++rep) {
        int flat = rep * 256 + tid;
        int cg = flat & 7, w = (flat >> 3) & 31, rp = flat >> 8;
        int row = h0 - 1 + rp;
        short8 v = {0, 0, 0, 0, 0, 0, 0, 0};
        if ((unsigned)row < 32u)
          v = *(const short8*)&xT[(b * 1024 + row * 32 + w) * 256 + c0 + cg * 8];
        *(short8*)&Xc[(rp * 34 + w + 1) * 72 + cg * 8] = v;
      }
      __syncthreads();
#pragma unroll
      for (int ks = 0; ks < 2; ++ks) {
        int ko = c0 + ks * 32 + g * 8;
        int klo = ks * 32 + g * 8;
#pragma unroll
        for (int r = 0; r < 3; ++r)
#pragma unroll
          for (int s = 0; s < 3; ++s) {
            int tap = r * 3 + s;
            short8 a0 = *(const short8*)&WcT[(tap * 256 + co0 + ln) * 256 + ko];
            short8 a1 =
                *(const short8*)&WcT[(tap * 256 + co0 + 16 + ln) * 256 + ko];
#pragma unroll
            for (int jt = 0; jt < 4; ++jt) {
              int rowp = ((jt >> 1) + r) * 34 + (jt & 1) * 16 + ln + s;
              short8 bf = *(const short8*)&Xc[rowp * 72 + klo];
              acc[0][jt] = __builtin_amdgcn_mfma_f32_16x16x32_bf16(
                  a0, bf, acc[0][jt], 0, 0, 0);
              acc[1][jt] = __builtin_amdgcn_mfma_f32_16x16x32_bf16(
                  a1, bf, acc[1][jt], 0, 0, 0);
            }
          }
      }
    }

#pragma unroll
    for (int it = 0; it < 2; ++it)
#pragma unroll
      for (int r4 = 0; r4 < 4; ++r4) {
        int co = co0 + it * 16 + g * 4 + r4;
        float bias = cb[co];
#pragma unroll
        for (int jt = 0; jt < 4; ++jt) {
          int h = h0 + (jt >> 1), w = (jt & 1) * 16 + ln;
          out[((b * 512 + co) * 32 + h) * 32 + w] = acc[it][jt][r4] + bias;
        }
      }
    return;
  }

  // ========================== attn (R7 body) ==========================
  u16* kvb = (u16*)smem;                  // kv[2][4096]: buf*4096
  u16* ps = (u16*)(smem + 16384);         // p_s[4][2][1024]
  int idx = trip * 2 + rem;               // 0..63
  int h = idx >> 3, qt = idx & 7;
  int nw = qt * 128 + wave * 32;

  const u16* kb = kT + (b * 8 + h) * (1024 * 32);
  const u16* qb = qT + (b * 8 + h) * (1024 * 32);
  const u16* vb = vB + (b * 256 + h * 32) * 1024;

  short8 qf0 = *(const short8*)&qb[(nw + ln) * 32 + g * 8];
  short8 qf1 = *(const short8*)&qb[(nw + 16 + ln) * 32 + g * 8];

  // staging coords: K piece (row sr, 16B slot ss), V piece (row dvr, slot vs)
  int sr = tid >> 2, ss = tid & 3;
  int dvr = tid >> 3, vs = tid & 7;
  const u16* ksrc = kb + sr * 32 + ss * 8;
  const u16* vsrc = vb + dvr * 1024 + vs * 8;
  int kdsw = sr * 32 + ((ss ^ ((sr + (sr >> 2)) & 3)) * 8);
  int vdsw = 2048 + dvr * 64 + ((vs ^ (dvr & 7)) * 8);

  // per-lane fragment swizzle constants
  int skl = (ln + (ln >> 2)) & 3;
  int svl = ln & 7;
  int kfo = ln * 32 + ((g ^ skl) * 8);   // K frag u16 offset (+ kt*512)

  f32x4 o00 = {0.f, 0.f, 0.f, 0.f}, o01 = o00, o10 = o00, o11 = o00;
  float mx0 = -1e30f, mx1 = -1e30f, l0 = 0.f, l1 = 0.f;
  u16* pw0 = ps + wave * 2048;
  u16* pw1 = pw0 + 1024;

  // prologue: tile 0 -> buf0; issue tile 1 loads
  short8 kp = *(const short8*)ksrc;
  short8 vp = *(const short8*)vsrc;
  *(short8*)&kvb[kdsw] = kp;
  *(short8*)&kvb[vdsw] = vp;
  __syncthreads();
  kp = *(const short8*)(ksrc + 2048);
  vp = *(const short8*)(vsrc + 64);

  for (int mt = 0; mt < 16; ++mt) {
    u16* bc = kvb + (mt & 1) * 4096;
    if (mt < 15) {
      u16* bn = kvb + ((mt + 1) & 1) * 4096;
      *(short8*)&bn[kdsw] = kp;
      *(short8*)&bn[vdsw] = vp;
    }
    if (mt < 14) {
      kp = *(const short8*)(ksrc + (mt + 2) * 2048);
      vp = *(const short8*)(vsrc + (mt + 2) * 64);
    }

    // ---- QK^T ----
    short8 ka0 = *(const short8*)&bc[0 * 512 + kfo];
    short8 ka1 = *(const short8*)&bc[1 * 512 + kfo];
    short8 ka2 = *(const short8*)&bc[2 * 512 + kfo];
    short8 ka3 = *(const short8*)&bc[3 * 512 + kfo];
    f32x4 z = {0.f, 0.f, 0.f, 0.f};
    f32x4 s0[4], s1[4];
    __builtin_amdgcn_s_setprio(1);
    s0[0] = __builtin_amdgcn_mfma_f32_16x16x32_bf16(ka0, qf0, z, 0, 0, 0);
    s1[0] = __builtin_amdgcn_mfma_f32_16x16x32_bf16(ka0, qf1, z, 0, 0, 0);
    s0[1] = __builtin_amdgcn_mfma_f32_16x16x32_bf16(ka1, qf0, z, 0, 0, 0);
    s1[1] = __builtin_amdgcn_mfma_f32_16x16x32_bf16(ka1, qf1, z, 0, 0, 0);
    s0[2] = __builtin_amdgcn_mfma_f32_16x16x32_bf16(ka2, qf0, z, 0, 0, 0);
    s1[2] = __builtin_amdgcn_mfma_f32_16x16x32_bf16(ka2, qf1, z, 0, 0, 0);
    s0[3] = __builtin_amdgcn_mfma_f32_16x16x32_bf16(ka3, qf0, z, 0, 0, 0);
    s1[3] = __builtin_amdgcn_mfma_f32_16x16x32_bf16(ka3, qf1, z, 0, 0, 0);
    __builtin_amdgcn_s_setprio(0);

    // V fragments (LDS, current buffer) -- prefetch for PV
    short8 va00 = *(const short8*)&bc[2048 + ln * 64 + ((g ^ svl) * 8)];
    short8 va01 = *(const short8*)&bc[2048 + (16 + ln) * 64 + ((g ^ svl) * 8)];
    short8 va10 = *(const short8*)&bc[2048 + ln * 64 + (((4 + g) ^ svl) * 8)];
    short8 va11 =
        *(const short8*)&bc[2048 + (16 + ln) * 64 + (((4 + g) ^ svl) * 8)];

    // ---- online softmax (exp2 domain), tree reductions ----
    float tmax0 = fmaxf(fmaxf(hmax4(s0[0]), hmax4(s0[1])),
                        fmaxf(hmax4(s0[2]), hmax4(s0[3])));
    float tmax1 = fmaxf(fmaxf(hmax4(s1[0]), hmax4(s1[1])),
                        fmaxf(hmax4(s1[2]), hmax4(s1[3])));
    tmax0 = fmaxf(tmax0, __shfl_xor(tmax0, 16));
    tmax0 = fmaxf(tmax0, __shfl_xor(tmax0, 32));
    tmax1 = fmaxf(tmax1, __shfl_xor(tmax1, 16));
    tmax1 = fmaxf(tmax1, __shfl_xor(tmax1, 32));

    if (!__all(fmaxf(tmax0 - mx0, tmax1 - mx1) <= 8.0f)) {
      float nm0 = fmaxf(mx0, tmax0), nm1 = fmaxf(mx1, tmax1);
      float sc0 = __builtin_amdgcn_exp2f(mx0 - nm0);
      float sc1 = __builtin_amdgcn_exp2f(mx1 - nm1);
#pragma unroll
      for (int r = 0; r < 4; ++r) {
        o00[r] *= sc0; o01[r] *= sc0;
        o10[r] *= sc1; o11[r] *= sc1;
      }
      l0 *= sc0; l1 *= sc1;
      mx0 = nm0; mx1 = nm1;
    }

#pragma unroll
    for (int kt = 0; kt < 4; ++kt)
#pragma unroll
      for (int r = 0; r < 4; ++r) {
        s0[kt][r] = __builtin_amdgcn_exp2f(s0[kt][r] - mx0);
        s1[kt][r] = __builtin_amdgcn_exp2f(s1[kt][r] - mx1);
      }
    float ts0 = (hsum4(s0[0]) + hsum4(s0[1])) + (hsum4(s0[2]) + hsum4(s0[3]));
    float ts1 = (hsum4(s1[0]) + hsum4(s1[1])) + (hsum4(s1[2]) + hsum4(s1[3]));
    ts0 += __shfl_xor(ts0, 16); ts0 += __shfl_xor(ts0, 32);
    ts1 += __shfl_xor(ts1, 16); ts1 += __shfl_xor(ts1, 32);
    l0 += ts0; l1 += ts1;

    // ---- P -> bf16, swizzled LDS, b64 writes ----
#pragma unroll
    for (int kt = 0; kt < 4; ++kt) {
      int po = ln * 64 + (((kt * 2 + (g >> 1)) ^ svl) * 8) + (g & 1) * 4;
      uint2 w0 = {packP(s0[kt][0], s0[kt][1]), packP(s0[kt][2], s0[kt][3])};
      *(uint2*)&pw0[po] = w0;
      uint2 w1 = {packP(s1[kt][0], s1[kt][1]), packP(s1[kt][2], s1[kt][3])};
      *(uint2*)&pw1[po] = w1;
    }
    short8 pb00 = *(const short8*)&pw0[ln * 64 + ((g ^ svl) * 8)];
    short8 pb01 = *(const short8*)&pw0[ln * 64 + (((4 + g) ^ svl) * 8)];
    short8 pb10 = *(const short8*)&pw1[ln * 64 + ((g ^ svl) * 8)];
    short8 pb11 = *(const short8*)&pw1[ln * 64 + (((4 + g) ^ svl) * 8)];

    // ---- PV ----
    __builtin_amdgcn_s_setprio(1);
    o00 = __builtin_amdgcn_mfma_f32_16x16x32_bf16(va00, pb00, o00, 0, 0, 0);
    o01 = __builtin_amdgcn_mfma_f32_16x16x32_bf16(va01, pb00, o01, 0, 0, 0);
    o00 = __builtin_amdgcn_mfma_f32_16x16x32_bf16(va10, pb01, o00, 0, 0, 0);
    o01 = __builtin_amdgcn_mfma_f32_16x16x32_bf16(va11, pb01, o01, 0, 0, 0);
    o10 = __builtin_amdgcn_mfma_f32_16x16x32_bf16(va00, pb10, o10, 0, 0, 0);
    o11 = __builtin_amdgcn_mfma_f32_16x16x32_bf16(va01, pb10, o11, 0, 0, 0);
    o10 = __builtin_amdgcn_mfma_f32_16x16x32_bf16(va10, pb11, o10, 0, 0, 0);
    o11 = __builtin_amdgcn_mfma_f32_16x16x32_bf16(va11, pb11, o11, 0, 0, 0);
    __builtin_amdgcn_s_setprio(0);

    __syncthreads();
  }

  float rl0 = 1.f / l0, rl1 = 1.f / l1;
  float* obase = out + (b * 512 + 256 + h * 32) * 1024;
  float* ob0 = obase + nw + ln;
  float* ob1 = obase + nw + 16 + ln;
#pragma unroll
  for (int r = 0; r < 4; ++r) {
    int dv0 = g * 4 + r;
    ob0[dv0 * 1024] = o00[r] * rl0;
    ob0[(16 + dv0) * 1024] = o01[r] * rl0;
    ob1[dv0 * 1024] = o10[r] * rl1;
    ob1[(16 + dv0) * 1024] = o11[r] * rl1;
  }
}

// ---------------------------------------------------------------------------
extern "C" void kernel_launch(void* const* d_in, const int* in_sizes, int n_in,
                              void* d_out, int out_size, void* d_ws,
                              size_t ws_size, hipStream_t stream) {
  const float* x  = (const float*)d_in[0];
  const float* cw = (const float*)d_in[1];
  const float* cb = (const float*)d_in[2];
  const float* aw = (const float*)d_in[3];
  const float* ab = (const float*)d_in[4];
  float* out = (float*)d_out;

  char* ws = (char*)d_ws;
  u16* vB  = (u16*)ws;                           //  4,194,304 B
  u16* kT  = (u16*)(ws + 4194304);               //  4,194,304 B
  u16* qT  = (u16*)(ws + 8388608);               //  4,194,304 B
  u16* xT  = (u16*)(ws + 12582912);              //  4,194,304 B
  u16* WcT = (u16*)(ws + 16777216);              //  1,179,648 B
  u16* WaT = (u16*)(ws + 17956864);              //    393,216 B

  prep_kernel<<<320, 256, 0, stream>>>(x, cw, aw, xT, WcT, WaT);
  kqv_kernel<<<768, 256, 0, stream>>>(xT, WaT, ab, kT, qT, vB);
  conv_attn_kernel<<<768, 256, 0, stream>>>(xT, WcT, cb, kT, qT, vB, out);
}

// Round 6
// 64.533 us; speedup vs baseline: 1.6112x; 1.0581x over previous
//
#include <hip/hip_runtime.h>

// AAConv: 3x3 conv (256->256) + 1x1 conv (256->768 kqv) + 8-head attention
// (HW=1024, DKH=DVH=32), out = concat([conv_out, attn_out]) (8,512,32,32) fp32.
//
// R10: conv Xc XOR-swizzle. R9's conv Xc reads were 8-way bank-conflicted
//   (row stride 72 u16 = 36 dw == 4 mod 32 -> bank = 4*((ln+g)&7); measured
//   2.75M conflict cycles in the fused kernel). Swizzle the 16B slot by row:
//   slot ^= (row&7), applied on stage-write AND fragment-read (halo zero
//   covers full rows -> swizzle-invariant). Everything else identical to R9.
//
// ws layout (bytes): vB @0 (4,194,304) | kT @4,194,304 (4,194,304)
//   | qT @8,388,608 (4,194,304) | xT @12,582,912 (4,194,304)
//   | WcT @16,777,216 (1,179,648) | WaT @17,956,864 (393,216)

typedef __attribute__((ext_vector_type(8))) short short8;
typedef __attribute__((ext_vector_type(4))) float f32x4;
typedef unsigned short u16;

// 1/sqrt(32) * log2(e): Q pre-scale folding softmax into exp2 domain.
#define QSCALE 0.25503487629898483f

__device__ inline u16 f2bf(float f) {
  unsigned u = __builtin_bit_cast(unsigned, f);
  return (u16)((u + 0x7FFFu + ((u >> 16) & 1u)) >> 16);
}
__device__ inline unsigned pack2bf(float a, float b) {
  return (unsigned)f2bf(a) | ((unsigned)f2bf(b) << 16);
}
// P-pack: round-half-up to bf16 then byte-perm the two hi16s together.
__device__ inline unsigned packP(float a, float b) {
  unsigned au = __builtin_bit_cast(unsigned, a) + 0x8000u;
  unsigned bu = __builtin_bit_cast(unsigned, b) + 0x8000u;
  return __builtin_amdgcn_perm(bu, au, 0x07060302u);
}
__device__ inline float hmax4(f32x4 v) {
  return fmaxf(fmaxf(v[0], v[1]), fmaxf(v[2], v[3]));
}
__device__ inline float hsum4(f32x4 v) { return (v[0] + v[1]) + (v[2] + v[3]); }

// ---------------------------------------------------------------------------
// prep: grid 320. (streaming, no reuse -> no swizzle)
// ---------------------------------------------------------------------------
__global__ __launch_bounds__(256) void prep_kernel(const float* __restrict__ x,
                                                   const float* __restrict__ cw,
                                                   const float* __restrict__ aw,
                                                   u16* __restrict__ xT,
                                                   u16* __restrict__ WcT,
                                                   u16* __restrict__ WaT) {
  __shared__ float T[64][65];
  int bid = blockIdx.x, tid = threadIdx.x;

  if (bid < 128) {
    int b = bid >> 4, n0 = (bid & 15) * 64;
#pragma unroll
    for (int rep = 0; rep < 2; ++rep) {
      int flat = rep * 256 + tid;          // 0..511
      int n = flat & 63, cg = flat >> 6;   // cg 0..7 -> 32 ci each
#pragma unroll
      for (int q = 0; q < 4; ++q) {
        short8 pk;
#pragma unroll
        for (int j = 0; j < 8; ++j)
          pk[j] =
              (short)f2bf(x[(b * 256 + cg * 32 + q * 8 + j) * 1024 + n0 + n]);
        *(short8*)&xT[(b * 1024 + n0 + n) * 256 + cg * 32 + q * 8] = pk;
      }
    }
    return;
  }

  int tt = bid - 128;
  int chunk = tt >> 4, t = tt & 15;
  int ci0 = (t & 3) * 64, r0 = (t >> 2) * 64;
  bool isconv = chunk < 9;
  float scale = (chunk == 10) ? QSCALE : 1.0f;

#pragma unroll
  for (int rep = 0; rep < 16; ++rep) {
    int flat = rep * 256 + tid;
    int i = flat >> 6, j = flat & 63;     // i = ci-local, j = dst-row-local
    T[i][j] = isconv ? cw[(chunk * 256 + ci0 + i) * 256 + r0 + j]
                     : aw[(ci0 + i) * 768 + (chunk - 9) * 256 + r0 + j];
  }
  __syncthreads();
#pragma unroll
  for (int rep = 0; rep < 4; ++rep) {
    int flat = rep * 256 + tid;
    int jj = flat >> 4, qq = flat & 15;   // dst row r0+jj, ci ci0+qq*4
    float v0 = T[qq * 4 + 0][jj] * scale;
    float v1 = T[qq * 4 + 1][jj] * scale;
    float v2 = T[qq * 4 + 2][jj] * scale;
    float v3 = T[qq * 4 + 3][jj] * scale;
    uint2 pk = {pack2bf(v0, v1), pack2bf(v2, v3)};
    if (isconv)
      *(uint2*)&WcT[(chunk * 256 + r0 + jj) * 256 + ci0 + qq * 4] = pk;
    else
      *(uint2*)&WaT[((chunk - 9) * 256 + r0 + jj) * 256 + ci0 + qq * 4] = pk;
  }
}

// ---------------------------------------------------------------------------
// kqv: GEMM [768x256]x[256x1024] per batch. grid 768. b = bid&7 (XCD-local).
// ---------------------------------------------------------------------------
__global__ __launch_bounds__(256) void kqv_kernel(const u16* __restrict__ xT,
                                                  const u16* __restrict__ WaT,
                                                  const float* __restrict__ ab,
                                                  u16* __restrict__ kT,
                                                  u16* __restrict__ qT,
                                                  u16* __restrict__ vB) {
  __shared__ __align__(16) u16 Tt[64 * 136];  // [n-local 64][o-local 128 +8 pad]
  int bid = blockIdx.x;
  int b = bid & 7, idx = bid >> 3;       // XCD-local batch
  int ot = idx >> 4, nt = idx & 15;      // idx 0..95 -> ot 0..5, nt 0..15
  int tid = threadIdx.x, wave = tid >> 6, lane = tid & 63;
  int ln = lane & 15, g = lane >> 4;
  int o0 = ot * 128 + (wave & 1) * 64;
  int n0 = nt * 64 + (wave >> 1) * 32;
  const u16* xb = xT + b * 1024 * 256;
  f32x4 acc[4][2];
#pragma unroll
  for (int i = 0; i < 4; ++i)
#pragma unroll
    for (int j = 0; j < 2; ++j) acc[i][j] = (f32x4){0.f, 0.f, 0.f, 0.f};

#pragma unroll
  for (int c0 = 0; c0 < 256; c0 += 32) {
    int ko = c0 + g * 8;
    short8 a0 = *(const short8*)&WaT[(o0 + ln) * 256 + ko];
    short8 a1 = *(const short8*)&WaT[(o0 + 16 + ln) * 256 + ko];
    short8 a2 = *(const short8*)&WaT[(o0 + 32 + ln) * 256 + ko];
    short8 a3 = *(const short8*)&WaT[(o0 + 48 + ln) * 256 + ko];
    short8 b0 = *(const short8*)&xb[(n0 + ln) * 256 + ko];
    short8 b1 = *(const short8*)&xb[(n0 + 16 + ln) * 256 + ko];
    acc[0][0] = __builtin_amdgcn_mfma_f32_16x16x32_bf16(a0, b0, acc[0][0], 0, 0, 0);
    acc[0][1] = __builtin_amdgcn_mfma_f32_16x16x32_bf16(a0, b1, acc[0][1], 0, 0, 0);
    acc[1][0] = __builtin_amdgcn_mfma_f32_16x16x32_bf16(a1, b0, acc[1][0], 0, 0, 0);
    acc[1][1] = __builtin_amdgcn_mfma_f32_16x16x32_bf16(a1, b1, acc[1][1], 0, 0, 0);
    acc[2][0] = __builtin_amdgcn_mfma_f32_16x16x32_bf16(a2, b0, acc[2][0], 0, 0, 0);
    acc[2][1] = __builtin_amdgcn_mfma_f32_16x16x32_bf16(a2, b1, acc[2][1], 0, 0, 0);
    acc[3][0] = __builtin_amdgcn_mfma_f32_16x16x32_bf16(a3, b0, acc[3][0], 0, 0, 0);
    acc[3][1] = __builtin_amdgcn_mfma_f32_16x16x32_bf16(a3, b1, acc[3][1], 0, 0, 0);
  }

  if (ot >= 4) {
    // V: natural [dv][m] layout, scalar bf16 stores.
#pragma unroll
    for (int it = 0; it < 4; ++it)
#pragma unroll
      for (int r = 0; r < 4; ++r) {
        int o = o0 + it * 16 + g * 4 + r;
        float bias = ab[o];
#pragma unroll
        for (int jt = 0; jt < 2; ++jt) {
          int n = n0 + jt * 16 + ln;
          vB[(b * 256 + (o - 512)) * 1024 + n] = f2bf(acc[it][jt][r] + bias);
        }
      }
    return;
  }

  // K/Q: transpose 128o x 64n tile via LDS, write [b][h][n][d] vectorized.
  bool isQ = (ot >= 2);
  float bs = isQ ? QSCALE : 1.0f;
  int olb = (wave & 1) * 64;
  int nlb = (wave >> 1) * 32;
#pragma unroll
  for (int it = 0; it < 4; ++it)
#pragma unroll
    for (int jt = 0; jt < 2; ++jt) {
      int ol = olb + it * 16 + g * 4;
      int nl = nlb + jt * 16 + ln;
      int og = ot * 128 + ol;
      float v0 = acc[it][jt][0] + ab[og + 0] * bs;
      float v1 = acc[it][jt][1] + ab[og + 1] * bs;
      float v2 = acc[it][jt][2] + ab[og + 2] * bs;
      float v3 = acc[it][jt][3] + ab[og + 3] * bs;
      uint2 pk = {pack2bf(v0, v1), pack2bf(v2, v3)};
      *(uint2*)&Tt[nl * 136 + ol] = pk;
    }
  __syncthreads();
  u16* dst = isQ ? qT : kT;
#pragma unroll
  for (int rep = 0; rep < 4; ++rep) {
    int flat = rep * 256 + tid;
    int o8 = flat & 15, nl = flat >> 4;
    short8 v = *(const short8*)&Tt[nl * 136 + o8 * 8];
    int og256 = (ot & 1) * 128 + o8 * 8;   // o within the 256-row K (or Q) range
    int hh = og256 >> 5, d0 = og256 & 31;
    int ng = nt * 64 + nl;
    *(short8*)&dst[((b * 8 + hh) * 1024 + ng) * 32 + d0] = v;
  }
}

// ---------------------------------------------------------------------------
// FUSED conv + attn. grid 768. xcd = bid&7 -> batch b; sub = bid>>3 (0..95);
// rem = sub%3: rem==2 -> conv idx=sub/3 (0..31), else attn idx=(sub/3)*2+rem.
//   conv (R7 geometry + Xc slot swizzle): hp = idx>>1 (2 h-rows), coh = idx&1.
//   attn: h = idx>>3, qt = idx&7 (128 q-rows per block, 4 waves x 32).
// LDS union: attn kv(16KB)+p_s(16KB) = 32KB; conv Xc 4*34*72 u16 = 19.6KB.
// ---------------------------------------------------------------------------
__global__ __launch_bounds__(256, 2) void conv_attn_kernel(
    const u16* __restrict__ xT, const u16* __restrict__ WcT,
    const float* __restrict__ cb, const u16* __restrict__ kT,
    const u16* __restrict__ qT, const u16* __restrict__ vB,
    float* __restrict__ out) {
  __shared__ __align__(16) unsigned char smem[32768];

  int bid = blockIdx.x;
  int b = bid & 7;                  // XCD-local batch
  int sub = bid >> 3;               // 0..95
  int trip = sub / 3;
  int rem = sub - trip * 3;
  int tid = threadIdx.x;
  int wave = tid >> 6, lane = tid & 63;
  int ln = lane & 15, g = lane >> 4;

  if (rem == 2) {
    // ========== conv: R7 body, Xc 16B-slot swizzled by row (slot^=row&7) =====
    u16* Xc = (u16*)smem;           // [4*34 rows][72], 19.6 KB
    int hp = trip >> 1, coh = trip & 1;
    int h0 = hp * 2;
    int co0 = coh * 128 + wave * 32;

    f32x4 acc[2][4];
#pragma unroll
    for (int i = 0; i < 2; ++i)
#pragma unroll
      for (int j = 0; j < 4; ++j) acc[i][j] = (f32x4){0.f, 0.f, 0.f, 0.f};

    {
      // zero full halo rows (w'=0 and w'=33): covers all 64 u16 of the row,
      // so it is swizzle-invariant.
      int rp = tid >> 6, rest = tid & 63;
      int which = rest >> 5, cp = rest & 31;
      *(unsigned*)&Xc[(rp * 34 + which * 33) * 72 + cp * 2] = 0u;
    }

    for (int c0 = 0; c0 < 256; c0 += 64) {
      __syncthreads();
#pragma unroll
      for (int rep = 0; rep < 4; ++rep) {
        int flat = rep * 256 + tid;
        int cg = flat & 7, w = (flat >> 3) & 31, rp = flat >> 8;
        int row = h0 - 1 + rp;
        short8 v = {0, 0, 0, 0, 0, 0, 0, 0};
        if ((unsigned)row < 32u)
          v = *(const short8*)&xT[(b * 1024 + row * 32 + w) * 256 + c0 + cg * 8];
        int rowS = rp * 34 + w + 1;
        *(short8*)&Xc[rowS * 72 + ((cg ^ (rowS & 7)) * 8)] = v;
      }
      __syncthreads();
#pragma unroll
      for (int ks = 0; ks < 2; ++ks) {
        int ko = c0 + ks * 32 + g * 8;
        int slot = ks * 4 + g;
#pragma unroll
        for (int r = 0; r < 3; ++r)
#pragma unroll
          for (int s = 0; s < 3; ++s) {
            int tap = r * 3 + s;
            short8 a0 = *(const short8*)&WcT[(tap * 256 + co0 + ln) * 256 + ko];
            short8 a1 =
                *(const short8*)&WcT[(tap * 256 + co0 + 16 + ln) * 256 + ko];
#pragma unroll
            for (int jt = 0; jt < 4; ++jt) {
              int rowp = ((jt >> 1) + r) * 34 + (jt & 1) * 16 + ln + s;
              short8 bf =
                  *(const short8*)&Xc[rowp * 72 + ((slot ^ (rowp & 7)) * 8)];
              acc[0][jt] = __builtin_amdgcn_mfma_f32_16x16x32_bf16(
                  a0, bf, acc[0][jt], 0, 0, 0);
              acc[1][jt] = __builtin_amdgcn_mfma_f32_16x16x32_bf16(
                  a1, bf, acc[1][jt], 0, 0, 0);
            }
          }
      }
    }

#pragma unroll
    for (int it = 0; it < 2; ++it)
#pragma unroll
      for (int r4 = 0; r4 < 4; ++r4) {
        int co = co0 + it * 16 + g * 4 + r4;
        float bias = cb[co];
#pragma unroll
        for (int jt = 0; jt < 4; ++jt) {
          int h = h0 + (jt >> 1), w = (jt & 1) * 16 + ln;
          out[((b * 512 + co) * 32 + h) * 32 + w] = acc[it][jt][r4] + bias;
        }
      }
    return;
  }

  // ========================== attn (R7 body) ==========================
  u16* kvb = (u16*)smem;                  // kv[2][4096]: buf*4096
  u16* ps = (u16*)(smem + 16384);         // p_s[4][2][1024]
  int idx = trip * 2 + rem;               // 0..63
  int h = idx >> 3, qt = idx & 7;
  int nw = qt * 128 + wave * 32;

  const u16* kb = kT + (b * 8 + h) * (1024 * 32);
  const u16* qb = qT + (b * 8 + h) * (1024 * 32);
  const u16* vb = vB + (b * 256 + h * 32) * 1024;

  short8 qf0 = *(const short8*)&qb[(nw + ln) * 32 + g * 8];
  short8 qf1 = *(const short8*)&qb[(nw + 16 + ln) * 32 + g * 8];

  // staging coords: K piece (row sr, 16B slot ss), V piece (row dvr, slot vs)
  int sr = tid >> 2, ss = tid & 3;
  int dvr = tid >> 3, vs = tid & 7;
  const u16* ksrc = kb + sr * 32 + ss * 8;
  const u16* vsrc = vb + dvr * 1024 + vs * 8;
  int kdsw = sr * 32 + ((ss ^ ((sr + (sr >> 2)) & 3)) * 8);
  int vdsw = 2048 + dvr * 64 + ((vs ^ (dvr & 7)) * 8);

  // per-lane fragment swizzle constants
  int skl = (ln + (ln >> 2)) & 3;
  int svl = ln & 7;
  int kfo = ln * 32 + ((g ^ skl) * 8);   // K frag u16 offset (+ kt*512)

  f32x4 o00 = {0.f, 0.f, 0.f, 0.f}, o01 = o00, o10 = o00, o11 = o00;
  float mx0 = -1e30f, mx1 = -1e30f, l0 = 0.f, l1 = 0.f;
  u16* pw0 = ps + wave * 2048;
  u16* pw1 = pw0 + 1024;

  // prologue: tile 0 -> buf0; issue tile 1 loads
  short8 kp = *(const short8*)ksrc;
  short8 vp = *(const short8*)vsrc;
  *(short8*)&kvb[kdsw] = kp;
  *(short8*)&kvb[vdsw] = vp;
  __syncthreads();
  kp = *(const short8*)(ksrc + 2048);
  vp = *(const short8*)(vsrc + 64);

  for (int mt = 0; mt < 16; ++mt) {
    u16* bc = kvb + (mt & 1) * 4096;
    if (mt < 15) {
      u16* bn = kvb + ((mt + 1) & 1) * 4096;
      *(short8*)&bn[kdsw] = kp;
      *(short8*)&bn[vdsw] = vp;
    }
    if (mt < 14) {
      kp = *(const short8*)(ksrc + (mt + 2) * 2048);
      vp = *(const short8*)(vsrc + (mt + 2) * 64);
    }

    // ---- QK^T ----
    short8 ka0 = *(const short8*)&bc[0 * 512 + kfo];
    short8 ka1 = *(const short8*)&bc[1 * 512 + kfo];
    short8 ka2 = *(const short8*)&bc[2 * 512 + kfo];
    short8 ka3 = *(const short8*)&bc[3 * 512 + kfo];
    f32x4 z = {0.f, 0.f, 0.f, 0.f};
    f32x4 s0[4], s1[4];
    __builtin_amdgcn_s_setprio(1);
    s0[0] = __builtin_amdgcn_mfma_f32_16x16x32_bf16(ka0, qf0, z, 0, 0, 0);
    s1[0] = __builtin_amdgcn_mfma_f32_16x16x32_bf16(ka0, qf1, z, 0, 0, 0);
    s0[1] = __builtin_amdgcn_mfma_f32_16x16x32_bf16(ka1, qf0, z, 0, 0, 0);
    s1[1] = __builtin_amdgcn_mfma_f32_16x16x32_bf16(ka1, qf1, z, 0, 0, 0);
    s0[2] = __builtin_amdgcn_mfma_f32_16x16x32_bf16(ka2, qf0, z, 0, 0, 0);
    s1[2] = __builtin_amdgcn_mfma_f32_16x16x32_bf16(ka2, qf1, z, 0, 0, 0);
    s0[3] = __builtin_amdgcn_mfma_f32_16x16x32_bf16(ka3, qf0, z, 0, 0, 0);
    s1[3] = __builtin_amdgcn_mfma_f32_16x16x32_bf16(ka3, qf1, z, 0, 0, 0);
    __builtin_amdgcn_s_setprio(0);

    // V fragments (LDS, current buffer) -- prefetch for PV
    short8 va00 = *(const short8*)&bc[2048 + ln * 64 + ((g ^ svl) * 8)];
    short8 va01 = *(const short8*)&bc[2048 + (16 + ln) * 64 + ((g ^ svl) * 8)];
    short8 va10 = *(const short8*)&bc[2048 + ln * 64 + (((4 + g) ^ svl) * 8)];
    short8 va11 =
        *(const short8*)&bc[2048 + (16 + ln) * 64 + (((4 + g) ^ svl) * 8)];

    // ---- online softmax (exp2 domain), tree reductions ----
    float tmax0 = fmaxf(fmaxf(hmax4(s0[0]), hmax4(s0[1])),
                        fmaxf(hmax4(s0[2]), hmax4(s0[3])));
    float tmax1 = fmaxf(fmaxf(hmax4(s1[0]), hmax4(s1[1])),
                        fmaxf(hmax4(s1[2]), hmax4(s1[3])));
    tmax0 = fmaxf(tmax0, __shfl_xor(tmax0, 16));
    tmax0 = fmaxf(tmax0, __shfl_xor(tmax0, 32));
    tmax1 = fmaxf(tmax1, __shfl_xor(tmax1, 16));
    tmax1 = fmaxf(tmax1, __shfl_xor(tmax1, 32));

    if (!__all(fmaxf(tmax0 - mx0, tmax1 - mx1) <= 8.0f)) {
      float nm0 = fmaxf(mx0, tmax0), nm1 = fmaxf(mx1, tmax1);
      float sc0 = __builtin_amdgcn_exp2f(mx0 - nm0);
      float sc1 = __builtin_amdgcn_exp2f(mx1 - nm1);
#pragma unroll
      for (int r = 0; r < 4; ++r) {
        o00[r] *= sc0; o01[r] *= sc0;
        o10[r] *= sc1; o11[r] *= sc1;
      }
      l0 *= sc0; l1 *= sc1;
      mx0 = nm0; mx1 = nm1;
    }

#pragma unroll
    for (int kt = 0; kt < 4; ++kt)
#pragma unroll
      for (int r = 0; r < 4; ++r) {
        s0[kt][r] = __builtin_amdgcn_exp2f(s0[kt][r] - mx0);
        s1[kt][r] = __builtin_amdgcn_exp2f(s1[kt][r] - mx1);
      }
    float ts0 = (hsum4(s0[0]) + hsum4(s0[1])) + (hsum4(s0[2]) + hsum4(s0[3]));
    float ts1 = (hsum4(s1[0]) + hsum4(s1[1])) + (hsum4(s1[2]) + hsum4(s1[3]));
    ts0 += __shfl_xor(ts0, 16); ts0 += __shfl_xor(ts0, 32);
    ts1 += __shfl_xor(ts1, 16); ts1 += __shfl_xor(ts1, 32);
    l0 += ts0; l1 += ts1;

    // ---- P -> bf16, swizzled LDS, b64 writes ----
#pragma unroll
    for (int kt = 0; kt < 4; ++kt) {
      int po = ln * 64 + (((kt * 2 + (g >> 1)) ^ svl) * 8) + (g & 1) * 4;
      uint2 w0 = {packP(s0[kt][0], s0[kt][1]), packP(s0[kt][2], s0[kt][3])};
      *(uint2*)&pw0[po] = w0;
      uint2 w1 = {packP(s1[kt][0], s1[kt][1]), packP(s1[kt][2], s1[kt][3])};
      *(uint2*)&pw1[po] = w1;
    }
    short8 pb00 = *(const short8*)&pw0[ln * 64 + ((g ^ svl) * 8)];
    short8 pb01 = *(const short8*)&pw0[ln * 64 + (((4 + g) ^ svl) * 8)];
    short8 pb10 = *(const short8*)&pw1[ln * 64 + ((g ^ svl) * 8)];
    short8 pb11 = *(const short8*)&pw1[ln * 64 + (((4 + g) ^ svl) * 8)];

    // ---- PV ----
    __builtin_amdgcn_s_setprio(1);
    o00 = __builtin_amdgcn_mfma_f32_16x16x32_bf16(va00, pb00, o00, 0, 0, 0);
    o01 = __builtin_amdgcn_mfma_f32_16x16x32_bf16(va01, pb00, o01, 0, 0, 0);
    o00 = __builtin_amdgcn_mfma_f32_16x16x32_bf16(va10, pb01, o00, 0, 0, 0);
    o01 = __builtin_amdgcn_mfma_f32_16x16x32_bf16(va11, pb01, o01, 0, 0, 0);
    o10 = __builtin_amdgcn_mfma_f32_16x16x32_bf16(va00, pb10, o10, 0, 0, 0);
    o11 = __builtin_amdgcn_mfma_f32_16x16x32_bf16(va01, pb10, o11, 0, 0, 0);
    o10 = __builtin_amdgcn_mfma_f32_16x16x32_bf16(va10, pb11, o10, 0, 0, 0);
    o11 = __builtin_amdgcn_mfma_f32_16x16x32_bf16(va11, pb11, o11, 0, 0, 0);
    __builtin_amdgcn_s_setprio(0);

    __syncthreads();
  }

  float rl0 = 1.f / l0, rl1 = 1.f / l1;
  float* obase = out + (b * 512 + 256 + h * 32) * 1024;
  float* ob0 = obase + nw + ln;
  float* ob1 = obase + nw + 16 + ln;
#pragma unroll
  for (int r = 0; r < 4; ++r) {
    int dv0 = g * 4 + r;
    ob0[dv0 * 1024] = o00[r] * rl0;
    ob0[(16 + dv0) * 1024] = o01[r] * rl0;
    ob1[dv0 * 1024] = o10[r] * rl1;
    ob1[(16 + dv0) * 1024] = o11[r] * rl1;
  }
}

// ---------------------------------------------------------------------------
extern "C" void kernel_launch(void* const* d_in, const int* in_sizes, int n_in,
                              void* d_out, int out_size, void* d_ws,
                              size_t ws_size, hipStream_t stream) {
  const float* x  = (const float*)d_in[0];
  const float* cw = (const float*)d_in[1];
  const float* cb = (const float*)d_in[2];
  const float* aw = (const float*)d_in[3];
  const float* ab = (const float*)d_in[4];
  float* out = (float*)d_out;

  char* ws = (char*)d_ws;
  u16* vB  = (u16*)ws;                           //  4,194,304 B
  u16* kT  = (u16*)(ws + 4194304);               //  4,194,304 B
  u16* qT  = (u16*)(ws + 8388608);               //  4,194,304 B
  u16* xT  = (u16*)(ws + 12582912);              //  4,194,304 B
  u16* WcT = (u16*)(ws + 16777216);              //  1,179,648 B
  u16* WaT = (u16*)(ws + 17956864);              //    393,216 B

  prep_kernel<<<320, 256, 0, stream>>>(x, cw, aw, xT, WcT, WaT);
  kqv_kernel<<<768, 256, 0, stream>>>(xT, WaT, ab, kT, qT, vB);
  conv_attn_kernel<<<768, 256, 0, stream>>>(xT, WcT, cb, kT, qT, vB, out);
}